// Round 4
// baseline (224.107 us; speedup 1.0000x reference)
//
#include <hip/hip_runtime.h>
#include <math.h>

// Cost weights / focal params (match reference)
#define W_CLASS 1.0f
#define W_BBOX  5.0f
#define W_GIOU  2.0f
#define F_ALPHA 0.25f
#define F_EPS   1e-8f

typedef float f2 __attribute__((ext_vector_type(2)));

#define ROWS 10            // pred rows per block (14400 = 1440 * 10)
#define TPB  320           // 5 waves; 3200 targets = 5 blocks * 320 thr * 2 tgt
#define TGT_PER_BLOCK (TPB * 2)

// v_rcp_f32 + one Newton step (kept bit-identical for softmax denominator)
__device__ __forceinline__ float fast_rcp_nr(float x) {
    float r = __builtin_amdgcn_rcpf(x);
    r = fmaf(fmaf(-x, r, 1.0f), r, r);
    return r;
}

// Fused kernel:
//  Phase A: each block computes the focal class-cost table for its ROWS pred
//           rows into LDS (one wave per 2 rows, identical math to the old
//           standalone class kernel -> bit-identical deltas).
//  Phase B: 2 targets per thread, all ROWS rows; delta gathers are ds_read
//           with compile-time row offsets; f2 nontemporal output stores.
__global__ __launch_bounds__(TPB)
void fused_cost_kernel(const float* __restrict__ logits,       // [N,128]
                       const float4* __restrict__ pred_boxes,  // [N,4] cxcywh
                       const float4* __restrict__ tgt_bbox,    // [T,4] cxcywh
                       const int* __restrict__ tgt_ids,        // [T]
                       float* __restrict__ out,                // [N,T]
                       int T) {
    __shared__ float delta[ROWS * 128];   // 5 KB

    const int n0 = blockIdx.y * ROWS;

    // ---------------- Phase A: class-cost table -> LDS ----------------
    {
        const int wave = threadIdx.x >> 6;
        const int lane = threadIdx.x & 63;
        #pragma unroll
        for (int rr = 0; rr < 2; ++rr) {
            const int lr = wave * 2 + rr;            // 0..9
            const int n = n0 + lr;
            f2 x = ((const f2*)(logits + (size_t)n * 128))[lane];

            float m = fmaxf(x.x, x.y);
            #pragma unroll
            for (int off = 32; off > 0; off >>= 1)
                m = fmaxf(m, __shfl_xor(m, off));

            float e0 = __expf(x.x - m);
            float e1 = __expf(x.y - m);
            float s = e0 + e1;
            #pragma unroll
            for (int off = 32; off > 0; off >>= 1)
                s += __shfl_xor(s, off);
            float inv = fast_rcp_nr(s);

            float p0 = e0 * inv, p1 = e1 * inv;
            float omp0 = 1.0f - p0, omp1 = 1.0f - p1;
            float d0 = F_ALPHA * omp0 * omp0 * (-__logf(p0 + F_EPS))
                     - (1.0f - F_ALPHA) * p0 * p0 * (-__logf(omp0 + F_EPS));
            float d1 = F_ALPHA * omp1 * omp1 * (-__logf(p1 + F_EPS))
                     - (1.0f - F_ALPHA) * p1 * p1 * (-__logf(omp1 + F_EPS));

            f2 o; o.x = d0; o.y = d1;
            ((f2*)(delta + lr * 128))[lane] = o;     // stride-8B write: conflict-free
        }
    }
    __syncthreads();

    // ---------------- Phase B: cost matrix ----------------
    const int t0 = (blockIdx.x * TPB + threadIdx.x) * 2;
    if (t0 >= T) return;   // no barriers below; uniform-true for T=3200

    const float4 tbA = tgt_bbox[t0];
    const float4 tbB = tgt_bbox[t0 + 1];
    const int idA = tgt_ids[t0];
    const int idB = tgt_ids[t0 + 1];

    // target xyxy + area (hoisted across all rows)
    const float ax0 = fmaf(-0.5f, tbA.z, tbA.x), ay0 = fmaf(-0.5f, tbA.w, tbA.y);
    const float ax1 = fmaf( 0.5f, tbA.z, tbA.x), ay1 = fmaf( 0.5f, tbA.w, tbA.y);
    const float areaA = tbA.z * tbA.w;
    const float bx0 = fmaf(-0.5f, tbB.z, tbB.x), by0 = fmaf(-0.5f, tbB.w, tbB.y);
    const float bx1 = fmaf( 0.5f, tbB.z, tbB.x), by1 = fmaf( 0.5f, tbB.w, tbB.y);
    const float areaB = tbB.z * tbB.w;

    const unsigned obase = (unsigned)n0 * (unsigned)T + (unsigned)t0;

    #pragma unroll
    for (int r = 0; r < ROWS; ++r) {
        const float4 pb = pred_boxes[n0 + r];        // block-uniform -> s_load
        const float px0 = fmaf(-0.5f, pb.z, pb.x), py0 = fmaf(-0.5f, pb.w, pb.y);
        const float px1 = fmaf( 0.5f, pb.z, pb.x), py1 = fmaf( 0.5f, pb.w, pb.y);
        const float parea = pb.z * pb.w;

        const float dA = delta[r * 128 + idA];       // ds_read, imm offset r*512
        const float dB = delta[r * 128 + idB];

        // ---- target A ----
        float cbA = fabsf(pb.x - tbA.x) + fabsf(pb.y - tbA.y)
                  + fabsf(pb.z - tbA.z) + fabsf(pb.w - tbA.w);
        float iwA = fmaxf(fminf(px1, ax1) - fmaxf(px0, ax0), 0.0f);
        float ihA = fmaxf(fminf(py1, ay1) - fmaxf(py0, ay0), 0.0f);
        float interA = iwA * ihA;
        float uniA = parea + areaA - interA;
        float ewA = fmaxf(px1, ax1) - fminf(px0, ax0);
        float ehA = fmaxf(py1, ay1) - fminf(py0, ay0);
        float eareaA = ewA * ehA;
        // giou = inter*rcp(uni) + uni*rcp(earea) - 1
        float termsA = fmaf(interA, __builtin_amdgcn_rcpf(uniA),
                            uniA * __builtin_amdgcn_rcpf(eareaA));
        // C = 5*cb + d + 2 - 2*terms
        float cA = fmaf(W_BBOX, cbA, dA + 2.0f);
        cA = fmaf(-W_GIOU, termsA, cA);

        // ---- target B ----
        float cbB = fabsf(pb.x - tbB.x) + fabsf(pb.y - tbB.y)
                  + fabsf(pb.z - tbB.z) + fabsf(pb.w - tbB.w);
        float iwB = fmaxf(fminf(px1, bx1) - fmaxf(px0, bx0), 0.0f);
        float ihB = fmaxf(fminf(py1, by1) - fmaxf(py0, by0), 0.0f);
        float interB = iwB * ihB;
        float uniB = parea + areaB - interB;
        float ewB = fmaxf(px1, bx1) - fminf(px0, bx0);
        float ehB = fmaxf(py1, by1) - fminf(py0, by0);
        float eareaB = ewB * ehB;
        float termsB = fmaf(interB, __builtin_amdgcn_rcpf(uniB),
                            uniB * __builtin_amdgcn_rcpf(eareaB));
        float cB = fmaf(W_BBOX, cbB, dB + 2.0f);
        cB = fmaf(-W_GIOU, termsB, cB);

        f2 o; o.x = cA; o.y = cB;
        // write-once, zero-reuse: bypass L2
        __builtin_nontemporal_store(o, (f2*)(out + (size_t)(obase + (unsigned)(r * T))));
    }
}

extern "C" void kernel_launch(void* const* d_in, const int* in_sizes, int n_in,
                              void* d_out, int out_size, void* d_ws, size_t ws_size,
                              hipStream_t stream) {
    const float* pred_logits = (const float*)d_in[0];   // [16,900,128] f32
    const float* pred_boxes  = (const float*)d_in[1];   // [16,900,4]  f32
    const int*   tgt_ids     = (const int*)d_in[2];     // [3200] int32
    const float* tgt_bbox    = (const float*)d_in[3];   // [3200,4] f32
    float* out = (float*)d_out;
    (void)d_ws; (void)ws_size;

    const int N = in_sizes[1] / 4;   // bs*Q = 14400
    const int T = in_sizes[2];       // 3200

    dim3 grid((T + TGT_PER_BLOCK - 1) / TGT_PER_BLOCK, N / ROWS);  // (5, 1440)
    fused_cost_kernel<<<grid, TPB, 0, stream>>>(
        pred_logits, (const float4*)pred_boxes, (const float4*)tgt_bbox,
        tgt_ids, out, T);
}